// Round 3
// baseline (144.506 us; speedup 1.0000x reference)
//
#include <hip/hip_runtime.h>
#include <hip/hip_fp16.h>
#include <math.h>

#define Bn 512
#define Ln 200
#define En 64
#define Hn 4
#define Dn 16
#define KS3 18            // Kh/Qh row stride (halves): 36 B = 9 words (odd -> conflict-free)
#define VS3 200           // Vt row stride (halves): 100 words (2-way = free)
#define QSC 0.36067376022224085f   // 0.25 * log2(e): folds softmax exp into 2^x

typedef _Float16 __f16;
typedef __fp16 fp16x2 __attribute__((ext_vector_type(2)));   // native return type of cvt_pkrtz
typedef __f16 f16x4 __attribute__((ext_vector_type(4)));
typedef __f16 f16x8 __attribute__((ext_vector_type(8)));
typedef float f32x4 __attribute__((ext_vector_type(4)));

#if __has_builtin(__builtin_amdgcn_exp2f)
__device__ __forceinline__ float fexp2(float x) { return __builtin_amdgcn_exp2f(x); }
#else
__device__ __forceinline__ float fexp2(float x) { return exp2f(x); }
#endif

__device__ __forceinline__ f16x8 pack8s(float4 a, float4 b, float4 pa, float4 pb) {
    f16x8 r;
    r[0] = (__f16)(a.x + pa.x); r[1] = (__f16)(a.y + pa.y);
    r[2] = (__f16)(a.z + pa.z); r[3] = (__f16)(a.w + pa.w);
    r[4] = (__f16)(b.x + pb.x); r[5] = (__f16)(b.y + pb.y);
    r[6] = (__f16)(b.z + pb.z); r[7] = (__f16)(b.w + pb.w);
    return r;
}
__device__ __forceinline__ f16x8 pack8(float4 a, float4 b) {
    f16x8 r;
    r[0] = (__f16)a.x; r[1] = (__f16)a.y; r[2] = (__f16)a.z; r[3] = (__f16)a.w;
    r[4] = (__f16)b.x; r[5] = (__f16)b.y; r[6] = (__f16)b.z; r[7] = (__f16)b.w;
    return r;
}

// Pack 4 f32 -> f16x4 via two v_cvt_pkrtz_f16_f32 (2 converts/op instead of 4 scalar cvt).
__device__ __forceinline__ f16x4 pack4rtz(float e0, float e1, float e2, float e3) {
    const fp16x2 lo = __builtin_amdgcn_cvt_pkrtz(e0, e1);
    const fp16x2 hi = __builtin_amdgcn_cvt_pkrtz(e2, e3);
    f16x4 r;
    r[0] = (__f16)lo[0]; r[1] = (__f16)lo[1];
    r[2] = (__f16)hi[0]; r[3] = (__f16)hi[1];
    return r;
}

// Attention inner loop, trip-count-specialized on the number of LIVE q-tiles (NI).
template<int NI>
__device__ __forceinline__ void attn_core(
    const __f16* __restrict__ Kh_, const __f16* __restrict__ Qh_, const __f16* __restrict__ Vt_,
    int qt0, int klo, int khi, int nt, int len, int quad, int ln16,
    f32x4 (&o2)[4], f32x4 (&lacc)[4])
{
    const f16x4 ones = {(__f16)1.f, (__f16)1.f, (__f16)1.f, (__f16)1.f};
    f16x4 qf[NI];
    #pragma unroll
    for (int i = 0; i < NI; ++i) {
        int qr = min((qt0 + i) * 16 + ln16, Ln - 1);
        qf[i] = *(const f16x4*)(Qh_ + qr * KS3 + quad * 4);
    }
    const bool needmask = (khi == nt);
    const int kfull = khi - (needmask ? 1 : 0);

    f16x4 kf = *(const f16x4*)(Kh_ + min(klo * 16 + ln16, Ln - 1) * KS3 + quad * 4);
    f16x4 vf = *(const f16x4*)(Vt_ + ln16 * VS3 + min(klo * 16 + quad * 4, Ln - 4));

    for (int kt = klo; kt < kfull; ++kt) {   // full tiles: no masking
        const int krn = min((kt + 1) * 16 + ln16, Ln - 1);
        const int vcn = min((kt + 1) * 16 + quad * 4, Ln - 4);
        const f16x4 kfn = *(const f16x4*)(Kh_ + krn * KS3 + quad * 4);
        const f16x4 vfn = *(const f16x4*)(Vt_ + ln16 * VS3 + vcn);
        f32x4 s[NI];
        #pragma unroll
        for (int i = 0; i < NI; ++i)
            s[i] = __builtin_amdgcn_mfma_f32_16x16x16f16(kf, qf[i], (f32x4){0,0,0,0}, 0, 0, 0);
        f16x4 pf[NI];
        #pragma unroll
        for (int i = 0; i < NI; ++i) {
            pf[i] = pack4rtz(fexp2(fminf(s[i][0], 14.5f)),   // 2^14.5 < fp16 max
                             fexp2(fminf(s[i][1], 14.5f)),
                             fexp2(fminf(s[i][2], 14.5f)),
                             fexp2(fminf(s[i][3], 14.5f)));
        }
        #pragma unroll
        for (int i = 0; i < NI; ++i) {
            o2[i]   = __builtin_amdgcn_mfma_f32_16x16x16f16(vf,   pf[i], o2[i],   0, 0, 0);
            lacc[i] = __builtin_amdgcn_mfma_f32_16x16x16f16(ones, pf[i], lacc[i], 0, 0, 0);  // rowsum
        }
        kf = kfn; vf = vfn;
    }
    if (needmask) {   // last tile: zero keys >= len
        const int kbase = (nt - 1) * 16 + quad * 4;
        f32x4 s[NI];
        #pragma unroll
        for (int i = 0; i < NI; ++i)
            s[i] = __builtin_amdgcn_mfma_f32_16x16x16f16(kf, qf[i], (f32x4){0,0,0,0}, 0, 0, 0);
        f16x4 pf[NI];
        #pragma unroll
        for (int i = 0; i < NI; ++i) {
            float e[4];
            #pragma unroll
            for (int j = 0; j < 4; ++j) {
                const bool kok = (kbase + j) < len;
                e[j] = kok ? fexp2(fminf(s[i][j], 14.5f)) : 0.f;
            }
            pf[i] = pack4rtz(e[0], e[1], e[2], e[3]);
        }
        #pragma unroll
        for (int i = 0; i < NI; ++i) {
            o2[i]   = __builtin_amdgcn_mfma_f32_16x16x16f16(vf,   pf[i], o2[i],   0, 0, 0);
            lacc[i] = __builtin_amdgcn_mfma_f32_16x16x16f16(ones, pf[i], lacc[i], 0, 0, 0);
        }
    }
}

// ============ Fully fused: proj + attention + pool + Wf ============
// Grid = (b, h, qh): 2 sub-blocks per (b,h). For nquad <= 2 (len <= 128) the qh==1 twin
// exits right after the len-reduce; qh==0 behaves as before (adaptive k-split waves).
// For nquad >= 3 (the heavy items that set the load-imbalance tail), each twin projects
// K/Q/V and runs attention on HALF the q-quads with a 2-way k-split per wave:
// heavy-item critical path ~halves, and the 2x grid refills CUs during the tail.
__global__ __launch_bounds__(256, 4) void fused_kernel(
    const float* __restrict__ input, const int* __restrict__ mask,
    const float* __restrict__ pos_enc,
    const float* __restrict__ Wk, const float* __restrict__ bk,
    const float* __restrict__ Wv, const float* __restrict__ bv,
    const float* __restrict__ Wq, const float* __restrict__ bq,
    const float* __restrict__ Wf, const float* __restrict__ bf_,
    float* __restrict__ out)
{
    __shared__ __align__(16) __f16 Kh[Ln * KS3];    // 7.2 KB  K[t][16]
    __shared__ __align__(16) __f16 Qh[Ln * KS3];    // 7.2 KB  Q[t][16] (pre-scaled QSC)
    __shared__ __align__(16) __f16 Vt[16 * VS3];    // 6.4 KB  V^T[vd][t]
    __shared__ float lred[4][4][16];                // 1 KB   partial softmax denominators
    __shared__ float red[4][16];
    __shared__ float ph[16];
    __shared__ int cnt_red[4];

    const int tid  = threadIdx.x;
    const int qh   = blockIdx.x & 1;
    const int bh   = blockIdx.x >> 1;
    const int b    = bh >> 2, h = bh & 3;
    const int wave = tid >> 6, lane = tid & 63;
    const int quad = lane >> 4, ln16 = lane & 15;

    // ---- mask load (1 per thread) issued first ----
    const int mv = (tid < Ln) ? mask[b * Ln + tid] : 0;

    // ---- len before anything len-dependent ----
    int c = (mv != 0) ? 1 : 0;
    #pragma unroll
    for (int off = 32; off; off >>= 1) c += __shfl_down(c, off, 64);
    if (lane == 0) cnt_red[wave] = c;
    __syncthreads();
    const int len = cnt_red[0] + cnt_red[1] + cnt_red[2] + cnt_red[3];
    const int nt = (len + 15) >> 4;
    const int nquad = (nt + 3) >> 2;
    const bool split = (nquad >= 3);

    if (qh == 1 && !split) return;   // light item: twin not needed (block-uniform)

    // ---- weight B-fragments for THIS head (16 channels; L2-hot) + biases ----
    f16x8 bfr[3][2];
    #pragma unroll
    for (int m = 0; m < 3; ++m) {
        const float* W = (m == 0) ? Wk : (m == 1) ? Wv : Wq;
        #pragma unroll
        for (int ks = 0; ks < 2; ++ks) {
            const float4* wp = (const float4*)(W + (size_t)(h * 16 + ln16) * 64) + (ks * 8 + quad * 2);
            bfr[m][ks] = pack8(wp[0], wp[1]);
        }
    }
    const int cg = h * 16 + ln16;
    const float bkv = bk[cg], bvv = bv[cg], bqv = bq[cg];

    // ---- projection over nt tiles; A-frags direct from global ----
    const float4* in4 = (const float4*)(input + (size_t)b * Ln * En);
    const float4* pe4 = (const float4*)pos_enc;

    for (int rt = wave; rt < nt; rt += 4) {
        const int R = rt * 16 + ln16;
        const bool rok = (R < Ln);
        f16x8 af[2];
        #pragma unroll
        for (int ks = 0; ks < 2; ++ks) {
            float4 xa = {0,0,0,0}, xb = {0,0,0,0}, pa = {0,0,0,0}, pb = {0,0,0,0};
            if (rok) {
                const int o4 = R * 16 + ks * 8 + quad * 2;
                xa = in4[o4]; xb = in4[o4 + 1];
                pa = pe4[o4]; pb = pe4[o4 + 1];
            }
            af[ks] = pack8s(xa, xb, pa, pb);
        }
        f32x4 acc[3];
        #pragma unroll
        for (int m = 0; m < 3; ++m) acc[m] = (f32x4){0,0,0,0};
        #pragma unroll
        for (int ks = 0; ks < 2; ++ks)
            #pragma unroll
            for (int m = 0; m < 3; ++m)
                acc[m] = __builtin_amdgcn_mfma_f32_16x16x32_f16(af[ks], bfr[m][ks], acc[m], 0, 0, 0);

        #pragma unroll
        for (int j = 0; j < 4; ++j) {
            const int t = rt * 16 + quad * 4 + j;
            if (t < Ln) {
                Kh[t * KS3 + ln16] = (__f16)(acc[0][j] + bkv);
                Qh[t * KS3 + ln16] = (__f16)((acc[2][j] + bqv) * QSC);
            }
        }
        const int vc0 = rt * 16 + quad * 4;
        if (vc0 < Ln) {
            f16x4 vp;
            #pragma unroll
            for (int j = 0; j < 4; ++j) vp[j] = (__f16)(acc[1][j] + bvv);
            *(f16x4*)(Vt + ln16 * VS3 + vc0) = vp;
        }
    }
    __syncthreads();   // K/Q/V visible

    // ---- attention: wave assignment ----
    // split:        wave -> quad g = qh + 2*(wave&1), k-half kh = wave>>1   (nkh=2)
    // nquad == 2:   wave -> quad g = wave&1,          k-half kh = wave>>1   (nkh=2)
    // nquad == 1:   wave -> quad 0,                   k-quarter kh = wave   (nkh=4)
    int g, kh, nkh;
    if (split)            { g = qh + 2 * (wave & 1); kh = wave >> 1; nkh = 2; }
    else if (nquad == 2)  { g = wave & 1;            kh = wave >> 1; nkh = 2; }
    else                  { g = 0;                   kh = wave;      nkh = 4; }
    const bool active = (g < nquad);
    const int nktp = (nt + nkh - 1) / nkh;
    const int klo = kh * nktp;
    const int khi = min(klo + nktp, nt);
    const int qt0 = 4 * g;

    f32x4 o2[4], lacc[4];
    #pragma unroll
    for (int i = 0; i < 4; ++i) { o2[i] = (f32x4){0,0,0,0}; lacc[i] = (f32x4){0,0,0,0}; }

    if (active && klo < khi) {
        // live q-tiles for this wave (wave-uniform) -> compile-time-specialized core
        const int ni = __builtin_amdgcn_readfirstlane(min(4, nt - qt0));
        switch (ni) {
            case 1:  attn_core<1>(Kh, Qh, Vt, qt0, klo, khi, nt, len, quad, ln16, o2, lacc); break;
            case 2:  attn_core<2>(Kh, Qh, Vt, qt0, klo, khi, nt, len, quad, ln16, o2, lacc); break;
            case 3:  attn_core<3>(Kh, Qh, Vt, qt0, klo, khi, nt, len, quad, ln16, o2, lacc); break;
            default: attn_core<4>(Kh, Qh, Vt, qt0, klo, khi, nt, len, quad, ln16, o2, lacc); break;
        }
    }

    // ---- denominators: lacc[i][0] = l[q=ln16] (replicated across rows by ones-MFMA) ----
    float l[4];
    #pragma unroll
    for (int i = 0; i < 4; ++i) l[i] = lacc[i][0];

    if (nkh > 1) {   // block-uniform: exchange partial denominators across key-split waves
        if (lane < 16) {
            #pragma unroll
            for (int i = 0; i < 4; ++i) lred[wave][i][lane] = l[i];
        }
        __syncthreads();
        const int slot = wave & 1;   // quad-slot; waves (slot, slot+2) share a quad when nkh==2
        #pragma unroll
        for (int i = 0; i < 4; ++i) {
            if (nkh == 2) l[i] = lred[slot][i][ln16] + lred[slot + 2][i][ln16];
            else          l[i] = lred[0][i][ln16] + lred[1][i][ln16]
                               + lred[2][i][ln16] + lred[3][i][ln16];
        }
    }

    f32x4 pool = {0.f, 0.f, 0.f, 0.f};
    if (active) {
        #pragma unroll
        for (int i = 0; i < 4; ++i) {
            const float rs = ((qt0 + i) * 16 + ln16 < len) ? 1.f / l[i] : 0.f;
            #pragma unroll
            for (int j = 0; j < 4; ++j) pool[j] = fmaf(o2[i][j], rs, pool[j]);
        }
    }

    // ---- reduce pool over 16 q-lanes; combine 4 waves; write ----
    #pragma unroll
    for (int j = 0; j < 4; ++j) {
        #pragma unroll
        for (int off = 1; off < 16; off <<= 1) pool[j] += __shfl_xor(pool[j], off, 64);
    }
    if (ln16 == 0) {
        #pragma unroll
        for (int j = 0; j < 4; ++j) red[wave][quad * 4 + j] = pool[j];
    }
    __syncthreads();
    if (tid < 16)
        ph[tid] = (red[0][tid] + red[1][tid] + red[2][tid] + red[3][tid]) / ((float)len + 1e-8f);
    __syncthreads();

    // ---- fused final projection: partial out[b,e] over i in [h*16, h*16+16) ----
    if (tid < 64) {
        const int e = tid;
        const float* wr = Wf + (size_t)e * 64 + h * 16;
        float a = (h == 0 && qh == 0) ? bf_[e] : 0.f;   // bias added exactly once
        #pragma unroll
        for (int i = 0; i < 16; ++i) a = fmaf(wr[i], ph[i], a);
        atomicAdd(out + b * En + e, a);
    }
}

extern "C" void kernel_launch(void* const* d_in, const int* in_sizes, int n_in,
                              void* d_out, int out_size, void* d_ws, size_t ws_size,
                              hipStream_t stream) {
    const float* input   = (const float*)d_in[0];
    const int*   mask    = (const int*)  d_in[1];
    const float* pos_enc = (const float*)d_in[2];
    const float* Wk      = (const float*)d_in[3];
    const float* bk      = (const float*)d_in[4];
    const float* Wv      = (const float*)d_in[5];
    const float* bv      = (const float*)d_in[6];
    const float* Wq      = (const float*)d_in[7];
    const float* bq      = (const float*)d_in[8];
    const float* Wf      = (const float*)d_in[9];
    const float* bf      = (const float*)d_in[10];

    float* out = (float*)d_out;
    hipMemsetAsync(out, 0, (size_t)Bn * En * sizeof(float), stream);   // zero accumulator

    fused_kernel<<<Bn * Hn * 2, 256, 0, stream>>>(input, mask, pos_enc,
                                                  Wk, bk, Wv, bv, Wq, bq, Wf, bf, out);
}

// Round 4
// 121.984 us; speedup vs baseline: 1.1846x; 1.1846x over previous
//
#include <hip/hip_runtime.h>
#include <hip/hip_fp16.h>
#include <math.h>

#define Bn 512
#define Ln 200
#define En 64
#define Hn 4
#define Dn 16
#define KS3 18            // Kh/Qh row stride (halves): 36 B = 9 words (odd -> conflict-free)
#define VS3 200           // Vt row stride (halves): 100 words (2-way = free)
#define QSC 0.36067376022224085f   // 0.25 * log2(e): folds softmax exp into 2^x

typedef _Float16 __f16;
typedef __fp16 fp16x2 __attribute__((ext_vector_type(2)));   // native return type of cvt_pkrtz
typedef __f16 f16x4 __attribute__((ext_vector_type(4)));
typedef __f16 f16x8 __attribute__((ext_vector_type(8)));
typedef float f32x4 __attribute__((ext_vector_type(4)));

#if __has_builtin(__builtin_amdgcn_exp2f)
__device__ __forceinline__ float fexp2(float x) { return __builtin_amdgcn_exp2f(x); }
#else
__device__ __forceinline__ float fexp2(float x) { return exp2f(x); }
#endif

__device__ __forceinline__ f16x8 pack8s(float4 a, float4 b, float4 pa, float4 pb) {
    f16x8 r;
    r[0] = (__f16)(a.x + pa.x); r[1] = (__f16)(a.y + pa.y);
    r[2] = (__f16)(a.z + pa.z); r[3] = (__f16)(a.w + pa.w);
    r[4] = (__f16)(b.x + pb.x); r[5] = (__f16)(b.y + pb.y);
    r[6] = (__f16)(b.z + pb.z); r[7] = (__f16)(b.w + pb.w);
    return r;
}
__device__ __forceinline__ f16x8 pack8(float4 a, float4 b) {
    f16x8 r;
    r[0] = (__f16)a.x; r[1] = (__f16)a.y; r[2] = (__f16)a.z; r[3] = (__f16)a.w;
    r[4] = (__f16)b.x; r[5] = (__f16)b.y; r[6] = (__f16)b.z; r[7] = (__f16)b.w;
    return r;
}

// Pack 4 f32 -> f16x4 via two v_cvt_pkrtz_f16_f32 (2 converts/op instead of 4 scalar cvt).
__device__ __forceinline__ f16x4 pack4rtz(float e0, float e1, float e2, float e3) {
    const fp16x2 lo = __builtin_amdgcn_cvt_pkrtz(e0, e1);
    const fp16x2 hi = __builtin_amdgcn_cvt_pkrtz(e2, e3);
    f16x4 r;
    r[0] = (__f16)lo[0]; r[1] = (__f16)lo[1];
    r[2] = (__f16)hi[0]; r[3] = (__f16)hi[1];
    return r;
}

// Attention inner loop, trip-count-specialized on the number of LIVE q-tiles (NI).
template<int NI>
__device__ __forceinline__ void attn_core(
    const __f16* __restrict__ Kh_, const __f16* __restrict__ Qh_, const __f16* __restrict__ Vt_,
    int qt0, int klo, int khi, int nt, int len, int quad, int ln16,
    f32x4 (&o2)[4], f32x4 (&lacc)[4])
{
    const f16x4 ones = {(__f16)1.f, (__f16)1.f, (__f16)1.f, (__f16)1.f};
    f16x4 qf[NI];
    #pragma unroll
    for (int i = 0; i < NI; ++i) {
        int qr = min((qt0 + i) * 16 + ln16, Ln - 1);
        qf[i] = *(const f16x4*)(Qh_ + qr * KS3 + quad * 4);
    }
    const bool needmask = (khi == nt);
    const int kfull = khi - (needmask ? 1 : 0);

    f16x4 kf = *(const f16x4*)(Kh_ + min(klo * 16 + ln16, Ln - 1) * KS3 + quad * 4);
    f16x4 vf = *(const f16x4*)(Vt_ + ln16 * VS3 + min(klo * 16 + quad * 4, Ln - 4));

    for (int kt = klo; kt < kfull; ++kt) {   // full tiles: no masking
        const int krn = min((kt + 1) * 16 + ln16, Ln - 1);
        const int vcn = min((kt + 1) * 16 + quad * 4, Ln - 4);
        const f16x4 kfn = *(const f16x4*)(Kh_ + krn * KS3 + quad * 4);
        const f16x4 vfn = *(const f16x4*)(Vt_ + ln16 * VS3 + vcn);
        f32x4 s[NI];
        #pragma unroll
        for (int i = 0; i < NI; ++i)
            s[i] = __builtin_amdgcn_mfma_f32_16x16x16f16(kf, qf[i], (f32x4){0,0,0,0}, 0, 0, 0);
        f16x4 pf[NI];
        #pragma unroll
        for (int i = 0; i < NI; ++i) {
            pf[i] = pack4rtz(fexp2(fminf(s[i][0], 14.5f)),   // 2^14.5 < fp16 max
                             fexp2(fminf(s[i][1], 14.5f)),
                             fexp2(fminf(s[i][2], 14.5f)),
                             fexp2(fminf(s[i][3], 14.5f)));
        }
        #pragma unroll
        for (int i = 0; i < NI; ++i) {
            o2[i]   = __builtin_amdgcn_mfma_f32_16x16x16f16(vf,   pf[i], o2[i],   0, 0, 0);
            lacc[i] = __builtin_amdgcn_mfma_f32_16x16x16f16(ones, pf[i], lacc[i], 0, 0, 0);  // rowsum
        }
        kf = kfn; vf = vfn;
    }
    if (needmask) {   // last tile: zero keys >= len
        const int kbase = (nt - 1) * 16 + quad * 4;
        f32x4 s[NI];
        #pragma unroll
        for (int i = 0; i < NI; ++i)
            s[i] = __builtin_amdgcn_mfma_f32_16x16x16f16(kf, qf[i], (f32x4){0,0,0,0}, 0, 0, 0);
        f16x4 pf[NI];
        #pragma unroll
        for (int i = 0; i < NI; ++i) {
            float e[4];
            #pragma unroll
            for (int j = 0; j < 4; ++j) {
                const bool kok = (kbase + j) < len;
                e[j] = kok ? fexp2(fminf(s[i][j], 14.5f)) : 0.f;
            }
            pf[i] = pack4rtz(e[0], e[1], e[2], e[3]);
        }
        #pragma unroll
        for (int i = 0; i < NI; ++i) {
            o2[i]   = __builtin_amdgcn_mfma_f32_16x16x16f16(vf,   pf[i], o2[i],   0, 0, 0);
            lacc[i] = __builtin_amdgcn_mfma_f32_16x16x16f16(ones, pf[i], lacc[i], 0, 0, 0);
        }
    }
}

// ============ Fully fused: proj + attention + pool + Wf. Block = (b, ONE head), 256 thr ============
// R3: latency attack. (1) XCD swizzle so the 4 head-blocks of one b share an L2 (input slice
// 3.3MB < 4MB L2/XCD). (2) First proj tile's input loads issued at t0, before the len-reduce
// (rows <=63 always valid -> speculative-safe). (3) Proj loop software-pipelined: next tile's
// input loads issued a full iteration ahead; pos_enc (L2-resident) loaded in-iteration.
__global__ __launch_bounds__(256, 4) void fused_kernel(
    const float* __restrict__ input, const int* __restrict__ mask,
    const float* __restrict__ pos_enc,
    const float* __restrict__ Wk, const float* __restrict__ bk,
    const float* __restrict__ Wv, const float* __restrict__ bv,
    const float* __restrict__ Wq, const float* __restrict__ bq,
    const float* __restrict__ Wf, const float* __restrict__ bf_,
    float* __restrict__ out)
{
    __shared__ __align__(16) __f16 Kh[Ln * KS3];    // 7.2 KB  K[t][16]
    __shared__ __align__(16) __f16 Qh[Ln * KS3];    // 7.2 KB  Q[t][16] (pre-scaled QSC)
    __shared__ __align__(16) __f16 Vt[16 * VS3];    // 6.4 KB  V^T[vd][t]
    __shared__ float lred[4][4][16];                // 1 KB   partial softmax denominators
    __shared__ float red[4][16];
    __shared__ float ph[16];
    __shared__ int cnt_red[4];

    const int tid  = threadIdx.x;
    // XCD-aware swizzle (grid 2048 = 8 XCD * 256): all 4 heads of a given b land on ONE XCD,
    // temporally adjacent -> input[b] is an L2 hit for 3 of the 4 blocks (was L3, ~450cy).
    const int lin  = ((blockIdx.x & 7) << 8) | (blockIdx.x >> 3);
    const int b    = lin >> 2, h = lin & 3;
    const int wave = tid >> 6, lane = tid & 63;
    const int quad = lane >> 4, ln16 = lane & 15;

    const float4* in4 = (const float4*)(input + (size_t)b * Ln * En);
    const float4* pe4 = (const float4*)pos_enc;

    // ---- speculative first-tile input loads (rows wave*16+ln16 <= 63 < Ln: always safe) ----
    float4 px0, px1, px2, px3;
    {
        const int o4 = (wave * 16 + ln16) * 16 + quad * 2;
        px0 = in4[o4];     px1 = in4[o4 + 1];
        px2 = in4[o4 + 8]; px3 = in4[o4 + 9];
    }

    // ---- mask load (reduce is its first consumer) ----
    const int mv = (tid < Ln) ? mask[b * Ln + tid] : 0;

    // ---- weight B-fragments for THIS head (16 channels; L2-hot) + biases ----
    f16x8 bfr[3][2];
    #pragma unroll
    for (int m = 0; m < 3; ++m) {
        const float* W = (m == 0) ? Wk : (m == 1) ? Wv : Wq;
        #pragma unroll
        for (int ks = 0; ks < 2; ++ks) {
            const float4* wp = (const float4*)(W + (size_t)(h * 16 + ln16) * 64) + (ks * 8 + quad * 2);
            bfr[m][ks] = pack8(wp[0], wp[1]);
        }
    }
    const int cg = h * 16 + ln16;
    const float bkv = bk[cg], bvv = bv[cg], bqv = bq[cg];

    // ---- len (shuffle reduce over mask) ----
    int c = (mv != 0) ? 1 : 0;
    #pragma unroll
    for (int off = 32; off; off >>= 1) c += __shfl_down(c, off, 64);
    if (lane == 0) cnt_red[wave] = c;
    __syncthreads();
    const int len = cnt_red[0] + cnt_red[1] + cnt_red[2] + cnt_red[3];
    const int nt = (len + 15) >> 4;

    // ---- projection over nt tiles; software-pipelined input loads ----
    for (int rt = wave; rt < nt; rt += 4) {
        const int R = rt * 16 + ln16;
        const bool rok = (R < Ln);
        const int o4 = R * 16 + quad * 2;

        // issue NEXT tile's input loads first (a full iteration of cover)
        const int rtn = rt + 4;
        const int Rn = rtn * 16 + ln16;
        float4 pxn0 = {0,0,0,0}, pxn1 = {0,0,0,0}, pxn2 = {0,0,0,0}, pxn3 = {0,0,0,0};
        if (rtn < nt && Rn < Ln) {
            const int o4n = Rn * 16 + quad * 2;
            pxn0 = in4[o4n];     pxn1 = in4[o4n + 1];
            pxn2 = in4[o4n + 8]; pxn3 = in4[o4n + 9];
        }
        // pos_enc loads (L2/L3-resident, short latency)
        float4 pp0 = {0,0,0,0}, pp1 = {0,0,0,0}, pp2 = {0,0,0,0}, pp3 = {0,0,0,0};
        if (rok) {
            pp0 = pe4[o4];     pp1 = pe4[o4 + 1];
            pp2 = pe4[o4 + 8]; pp3 = pe4[o4 + 9];
        }
        // px holds zeros automatically when !rok (prefetch guard zero-fills)
        f16x8 af0 = pack8s(px0, px1, pp0, pp1);
        f16x8 af1 = pack8s(px2, px3, pp2, pp3);

        f32x4 acc[3];
        #pragma unroll
        for (int m = 0; m < 3; ++m) acc[m] = (f32x4){0,0,0,0};
        #pragma unroll
        for (int m = 0; m < 3; ++m)
            acc[m] = __builtin_amdgcn_mfma_f32_16x16x32_f16(af0, bfr[m][0], acc[m], 0, 0, 0);
        #pragma unroll
        for (int m = 0; m < 3; ++m)
            acc[m] = __builtin_amdgcn_mfma_f32_16x16x32_f16(af1, bfr[m][1], acc[m], 0, 0, 0);

        #pragma unroll
        for (int j = 0; j < 4; ++j) {
            const int t = rt * 16 + quad * 4 + j;
            if (t < Ln) {
                Kh[t * KS3 + ln16] = (__f16)(acc[0][j] + bkv);
                Qh[t * KS3 + ln16] = (__f16)((acc[2][j] + bqv) * QSC);
            }
        }
        const int vc0 = rt * 16 + quad * 4;
        if (vc0 < Ln) {
            f16x4 vp;
            #pragma unroll
            for (int j = 0; j < 4; ++j) vp[j] = (__f16)(acc[1][j] + bvv);
            *(f16x4*)(Vt + ln16 * VS3 + vc0) = vp;
        }
        px0 = pxn0; px1 = pxn1; px2 = pxn2; px3 = pxn3;   // rotate pipeline buffer
    }
    __syncthreads();   // K/Q/V visible

    // ---- attention: adaptive wave assignment over q-quads / key-splits ----
    const int nquad = (nt + 3) >> 2;
    int g, kh, nkh;
    if (nquad >= 3)      { g = wave;     kh = 0;         nkh = 1; }
    else if (nquad == 2) { g = wave & 1; kh = wave >> 1; nkh = 2; }
    else                 { g = 0;        kh = wave;      nkh = 4; }
    const bool active = (g < nquad);
    const int nktp = (nt + nkh - 1) / nkh;
    const int klo = kh * nktp;
    const int khi = min(klo + nktp, nt);
    const int qt0 = 4 * g;

    f32x4 o2[4], lacc[4];
    #pragma unroll
    for (int i = 0; i < 4; ++i) { o2[i] = (f32x4){0,0,0,0}; lacc[i] = (f32x4){0,0,0,0}; }

    if (active && klo < khi) {
        // live q-tiles for this wave (wave-uniform) -> compile-time-specialized core
        const int ni = __builtin_amdgcn_readfirstlane(min(4, nt - qt0));
        switch (ni) {
            case 1:  attn_core<1>(Kh, Qh, Vt, qt0, klo, khi, nt, len, quad, ln16, o2, lacc); break;
            case 2:  attn_core<2>(Kh, Qh, Vt, qt0, klo, khi, nt, len, quad, ln16, o2, lacc); break;
            case 3:  attn_core<3>(Kh, Qh, Vt, qt0, klo, khi, nt, len, quad, ln16, o2, lacc); break;
            default: attn_core<4>(Kh, Qh, Vt, qt0, klo, khi, nt, len, quad, ln16, o2, lacc); break;
        }
    }

    // ---- denominators: lacc[i][0] = l[q=ln16] (replicated across rows by ones-MFMA) ----
    float l[4];
    #pragma unroll
    for (int i = 0; i < 4; ++i) l[i] = lacc[i][0];

    if (nkh > 1) {   // block-uniform: exchange partial denominators across key-split waves
        if (lane < 16) {
            #pragma unroll
            for (int i = 0; i < 4; ++i) lred[wave][i][lane] = l[i];
        }
        __syncthreads();
        #pragma unroll
        for (int i = 0; i < 4; ++i) {
            if (nkh == 2) l[i] = lred[g][i][ln16] + lred[g + 2][i][ln16];
            else          l[i] = lred[0][i][ln16] + lred[1][i][ln16]
                               + lred[2][i][ln16] + lred[3][i][ln16];
        }
    }

    f32x4 pool = {0.f, 0.f, 0.f, 0.f};
    if (active) {
        #pragma unroll
        for (int i = 0; i < 4; ++i) {
            const float rs = ((qt0 + i) * 16 + ln16 < len) ? 1.f / l[i] : 0.f;
            #pragma unroll
            for (int j = 0; j < 4; ++j) pool[j] = fmaf(o2[i][j], rs, pool[j]);
        }
    }

    // ---- reduce pool over 16 q-lanes; combine 4 waves; write ----
    #pragma unroll
    for (int j = 0; j < 4; ++j) {
        #pragma unroll
        for (int off = 1; off < 16; off <<= 1) pool[j] += __shfl_xor(pool[j], off, 64);
    }
    if (ln16 == 0) {
        #pragma unroll
        for (int j = 0; j < 4; ++j) red[wave][quad * 4 + j] = pool[j];
    }
    __syncthreads();
    if (tid < 16)
        ph[tid] = (red[0][tid] + red[1][tid] + red[2][tid] + red[3][tid]) / ((float)len + 1e-8f);
    __syncthreads();

    // ---- fused final projection: partial out[b,e] over i in [h*16, h*16+16) ----
    if (tid < 64) {
        const int e = tid;
        const float* wr = Wf + (size_t)e * 64 + h * 16;
        float a = (h == 0) ? bf_[e] : 0.f;
        #pragma unroll
        for (int i = 0; i < 16; ++i) a = fmaf(wr[i], ph[i], a);
        atomicAdd(out + b * En + e, a);
    }
}

extern "C" void kernel_launch(void* const* d_in, const int* in_sizes, int n_in,
                              void* d_out, int out_size, void* d_ws, size_t ws_size,
                              hipStream_t stream) {
    const float* input   = (const float*)d_in[0];
    const int*   mask    = (const int*)  d_in[1];
    const float* pos_enc = (const float*)d_in[2];
    const float* Wk      = (const float*)d_in[3];
    const float* bk      = (const float*)d_in[4];
    const float* Wv      = (const float*)d_in[5];
    const float* bv      = (const float*)d_in[6];
    const float* Wq      = (const float*)d_in[7];
    const float* bq      = (const float*)d_in[8];
    const float* Wf      = (const float*)d_in[9];
    const float* bf      = (const float*)d_in[10];

    float* out = (float*)d_out;
    hipMemsetAsync(out, 0, (size_t)Bn * En * sizeof(float), stream);   // zero accumulator

    fused_kernel<<<Bn * Hn, 256, 0, stream>>>(input, mask, pos_enc,
                                              Wk, bk, Wv, bv, Wq, bq, Wf, bf, out);
}